// Round 3
// baseline (877.478 us; speedup 1.0000x reference)
//
#include <hip/hip_runtime.h>

typedef float  f32x4_t  __attribute__((ext_vector_type(4)));
typedef __bf16 bf16x8_t __attribute__((ext_vector_type(8)));

#define BS   512
#define Mn   64
#define Kn   32
#define Fn   64
#define ROWS 2048   // Mn*Kn
#define PAD  65
#define NW   8      // waves per block
#define NIT  16     // main-loop iterations per wave (128 tiles / 8 waves)

// launch_bounds 2nd arg is min BLOCKS/CU (CUDA semantics): 2 blocks * 8 waves
// = 16 waves/CU = 4 waves/SIMD -> VGPR cap 128. Round-2's (512,4) capped at 64
// and spilled ~1.4 GB to scratch.
__global__ __launch_bounds__(512, 2) void gnn_fused(
    const float* __restrict__ z_mk, const float* __restrict__ z_m,
    const float* __restrict__ z_k,  const float* __restrict__ Wedge,
    const float* __restrict__ Wm,   const float* __restrict__ Wk,
    const float* __restrict__ Wself_m, const float* __restrict__ Wself_k,
    const float* __restrict__ Wneigh_m, const float* __restrict__ Wneigh_k,
    float* __restrict__ out0, float* __restrict__ out1, float* __restrict__ out2)
{
    __shared__ __align__(16) float s_wzm[Mn * PAD];          // 4160
    __shared__ __align__(16) float s_wzk[Kn * PAD];          // 2080
    __shared__ __align__(16) float s_r1[Mn * Fn + Kn * Fn];  // 6144 (union region)

    const int tid  = threadIdx.x;
    const int b    = blockIdx.x;
    const int lane = tid & 63;
    const int wave = tid >> 6;     // 0..7
    const int low  = lane & 15;
    const int gr   = lane >> 4;
    const int f    = lane;         // feature index for head/tail
    const int rg   = wave;         // row group for head/tail

    float* s_zm  = s_r1;             // 4096 floats (head phase)
    float* s_zk  = s_r1 + Mn * Fn;   // 2048 floats (head phase)
    float* s_we  = s_r1;             // 4160 floats (frag-build phase)
    float* s_mnm = s_r1;             // 4096 floats (msg phase)
    float* s_mnk = s_r1 + Mn * Fn;   // 2048 floats (msg phase)

    // ---------------- P0: stage z_m, z_k ----------------
    {
        const float4* zms = (const float4*)(z_m + (size_t)b * Mn * Fn);
        float4* zmd = (float4*)s_zm;
        for (int i = tid; i < Mn * Fn / 4; i += 512) zmd[i] = zms[i];
        const float4* zks = (const float4*)(z_k + (size_t)b * Kn * Fn);
        float4* zkd = (float4*)s_zk;
        for (int i = tid; i < Kn * Fn / 4; i += 512) zkd[i] = zks[i];
    }
    __syncthreads();

    // ---------------- P1: head matmuls (fp32) ----------------
    float selfm_reg[8];
    float selfk_reg[4];
    {
        float accA[8], accB[8];
        #pragma unroll
        for (int t = 0; t < 8; ++t) { accA[t] = 0.f; accB[t] = 0.f; }
        for (int c0 = 0; c0 < Fn; c0 += 16) {
            float wA[16], wB[16];
            #pragma unroll
            for (int cc = 0; cc < 16; ++cc) {
                wA[cc] = Wm[(c0 + cc) * Fn + f];
                wB[cc] = Wself_m[(c0 + cc) * Fn + f];
            }
            #pragma unroll
            for (int t = 0; t < 8; ++t) {
                const float* zp = s_zm + (rg + 8 * t) * Fn + c0;
                #pragma unroll
                for (int q = 0; q < 4; ++q) {
                    float4 z = *(const float4*)(zp + q * 4);
                    accA[t] += z.x * wA[4*q] + z.y * wA[4*q+1] + z.z * wA[4*q+2] + z.w * wA[4*q+3];
                    accB[t] += z.x * wB[4*q] + z.y * wB[4*q+1] + z.z * wB[4*q+2] + z.w * wB[4*q+3];
                }
            }
        }
        #pragma unroll
        for (int t = 0; t < 8; ++t) {
            s_wzm[(rg + 8 * t) * PAD + f] = accA[t];
            selfm_reg[t] = accB[t];
        }
    }
    {
        float accA[4], accB[4];
        #pragma unroll
        for (int t = 0; t < 4; ++t) { accA[t] = 0.f; accB[t] = 0.f; }
        for (int c0 = 0; c0 < Fn; c0 += 16) {
            float wA[16], wB[16];
            #pragma unroll
            for (int cc = 0; cc < 16; ++cc) {
                wA[cc] = Wk[(c0 + cc) * Fn + f];
                wB[cc] = Wself_k[(c0 + cc) * Fn + f];
            }
            #pragma unroll
            for (int t = 0; t < 4; ++t) {
                const float* zp = s_zk + (rg + 8 * t) * Fn + c0;
                #pragma unroll
                for (int q = 0; q < 4; ++q) {
                    float4 z = *(const float4*)(zp + q * 4);
                    accA[t] += z.x * wA[4*q] + z.y * wA[4*q+1] + z.z * wA[4*q+2] + z.w * wA[4*q+3];
                    accB[t] += z.x * wB[4*q] + z.y * wB[4*q+1] + z.z * wB[4*q+2] + z.w * wB[4*q+3];
                }
            }
        }
        #pragma unroll
        for (int t = 0; t < 4; ++t) {
            s_wzk[(rg + 8 * t) * PAD + f] = accA[t];
            selfk_reg[t] = accB[t];
        }
    }
    __syncthreads();   // z_m/z_k staging now dead

    // ---------------- P2: stage Wedge (padded) ----------------
    for (int i = tid; i < Fn * Fn; i += 512)
        s_we[(i >> 6) * PAD + (i & 63)] = Wedge[i];
    __syncthreads();

    // ---------------- P3: build B fragments (bf16) ----------------
    bf16x8_t Bf[2][4];
    #pragma unroll
    for (int ks = 0; ks < 2; ++ks)
        #pragma unroll
        for (int n = 0; n < 4; ++n)
            #pragma unroll
            for (int i = 0; i < 8; ++i)
                Bf[ks][n][i] = (__bf16)s_we[(ks * 32 + gr * 8 + i) * PAD + n * 16 + low];
    __syncthreads();   // s_we dead

    // ---------------- P4: zero message accumulators ----------------
    for (int i = tid; i < Mn * Fn + Kn * Fn; i += 512) s_r1[i] = 0.f;
    __syncthreads();

    // ---------------- P5: main edge loop (MFMA) ----------------
    float nk[4][4];
    #pragma unroll
    for (int j = 0; j < 4; ++j)
        #pragma unroll
        for (int n = 0; n < 4; ++n) nk[j][n] = 0.f;

    const int p = wave & 1;            // tile parity fixed per wave (stride-8 tiles)
    const size_t browbase = (size_t)b * ROWS;

    for (int it = 0; it < NIT; ++it) {
        const int t = wave + NW * it;  // 0..127
        const int rbase = t * 16;
        const int m = t >> 1;
        const float* zr = z_mk + (browbase + rbase + low) * 64;

        bf16x8_t A[2];
        #pragma unroll
        for (int ks = 0; ks < 2; ++ks) {
            float4 q0 = *(const float4*)(zr + ks * 32 + gr * 8);
            float4 q1 = *(const float4*)(zr + ks * 32 + gr * 8 + 4);
            A[ks][0] = (__bf16)q0.x; A[ks][1] = (__bf16)q0.y;
            A[ks][2] = (__bf16)q0.z; A[ks][3] = (__bf16)q0.w;
            A[ks][4] = (__bf16)q1.x; A[ks][5] = (__bf16)q1.y;
            A[ks][6] = (__bf16)q1.z; A[ks][7] = (__bf16)q1.w;
        }

        f32x4_t acc[4];
        #pragma unroll
        for (int n = 0; n < 4; ++n) acc[n] = (f32x4_t){0.f, 0.f, 0.f, 0.f};
        #pragma unroll
        for (int ks = 0; ks < 2; ++ks)
            #pragma unroll
            for (int n = 0; n < 4; ++n)
                acc[n] = __builtin_amdgcn_mfma_f32_16x16x32_bf16(A[ks], Bf[ks][n], acc[n], 0, 0, 0);

        #pragma unroll
        for (int n = 0; n < 4; ++n) {
            const int fc = n * 16 + low;
            const float wmv = s_wzm[m * PAD + fc];
            float snm = 0.f;
            #pragma unroll
            for (int j = 0; j < 4; ++j) {
                const int kk = p * 16 + gr * 4 + j;    // == (rbase + gr*4 + j) & 31
                float e = acc[n][j] + wmv + s_wzk[kk * PAD + fc];
                e = e > 0.f ? e : 0.01f * e;
                out0[(browbase + rbase + gr * 4 + j) * 64 + fc] = e;
                nk[j][n] += e;
                snm += e;
            }
            snm += __shfl_xor(snm, 16);
            snm += __shfl_xor(snm, 32);
            if (gr == 0) atomicAdd(&s_mnm[m * Fn + fc], snm);
        }
    }

    // flush per-lane msg_nk partials
    #pragma unroll
    for (int j = 0; j < 4; ++j)
        #pragma unroll
        for (int n = 0; n < 4; ++n)
            atomicAdd(&s_mnk[(p * 16 + gr * 4 + j) * Fn + n * 16 + low], nk[j][n]);
    __syncthreads();

    // ---------------- P6: tail node updates (fp32) ----------------
    {
        float d[8];
        #pragma unroll
        for (int t = 0; t < 8; ++t) d[t] = 0.f;
        for (int c0 = 0; c0 < Fn; c0 += 16) {
            float w[16];
            #pragma unroll
            for (int cc = 0; cc < 16; ++cc) w[cc] = Wneigh_m[(c0 + cc) * Fn + f];
            #pragma unroll
            for (int t = 0; t < 8; ++t) {
                const float* mp = s_mnm + (rg + 8 * t) * Fn + c0;
                #pragma unroll
                for (int q = 0; q < 4; ++q) {
                    float4 z = *(const float4*)(mp + q * 4);
                    d[t] += z.x * w[4*q] + z.y * w[4*q+1] + z.z * w[4*q+2] + z.w * w[4*q+3];
                }
            }
        }
        #pragma unroll
        for (int t = 0; t < 8; ++t) {
            float v = selfm_reg[t] + d[t] * (1.f / 32.f);
            v = v > 0.f ? v : 0.01f * v;
            out1[(size_t)b * Mn * Fn + (rg + 8 * t) * Fn + f] = v;
        }
    }
    {
        float d[4];
        #pragma unroll
        for (int t = 0; t < 4; ++t) d[t] = 0.f;
        for (int c0 = 0; c0 < Fn; c0 += 16) {
            float w[16];
            #pragma unroll
            for (int cc = 0; cc < 16; ++cc) w[cc] = Wneigh_k[(c0 + cc) * Fn + f];
            #pragma unroll
            for (int t = 0; t < 4; ++t) {
                const float* mp = s_mnk + (rg + 8 * t) * Fn + c0;
                #pragma unroll
                for (int q = 0; q < 4; ++q) {
                    float4 z = *(const float4*)(mp + q * 4);
                    d[t] += z.x * w[4*q] + z.y * w[4*q+1] + z.z * w[4*q+2] + z.w * w[4*q+3];
                }
            }
        }
        #pragma unroll
        for (int t = 0; t < 4; ++t) {
            float v = selfk_reg[t] + d[t] * (1.f / 64.f);
            v = v > 0.f ? v : 0.01f * v;
            out2[(size_t)b * Kn * Fn + (rg + 8 * t) * Fn + f] = v;
        }
    }
}

extern "C" void kernel_launch(void* const* d_in, const int* in_sizes, int n_in,
                              void* d_out, int out_size, void* d_ws, size_t ws_size,
                              hipStream_t stream) {
    const float* z_mk     = (const float*)d_in[0];
    const float* z_m      = (const float*)d_in[1];
    const float* z_k      = (const float*)d_in[2];
    const float* Wedge    = (const float*)d_in[3];
    const float* Wm       = (const float*)d_in[4];
    const float* Wk       = (const float*)d_in[5];
    const float* Wself_m  = (const float*)d_in[6];
    const float* Wself_k  = (const float*)d_in[7];
    const float* Wneigh_m = (const float*)d_in[8];
    const float* Wneigh_k = (const float*)d_in[9];

    float* out0 = (float*)d_out;                       // (512, 2048, 64)
    float* out1 = out0 + (size_t)BS * ROWS * Fn;       // (512, 64, 64)
    float* out2 = out1 + (size_t)BS * Mn * Fn;         // (512, 32, 64)

    gnn_fused<<<BS, 512, 0, stream>>>(z_mk, z_m, z_k, Wedge, Wm, Wk,
                                      Wself_m, Wself_k, Wneigh_m, Wneigh_k,
                                      out0, out1, out2);
}

// Round 4
// 204.790 us; speedup vs baseline: 4.2848x; 4.2848x over previous
//
#include <hip/hip_runtime.h>

typedef float  f32x4_t  __attribute__((ext_vector_type(4)));
typedef __bf16 bf16x8_t __attribute__((ext_vector_type(8)));

#define BS   512
#define Mn   64
#define Kn   32
#define Fn   64
#define ROWS 2048   // Mn*Kn

// ---------------- Kernel A: edges + messages -----------------
// grid 2048 = 512 batches x 4 m-quarters; 256 threads (4 waves).
// LDS float layout, total 8480 floats (33.9 KB):
//   [0:1024)    s_wzm  (16 x 64, broadcast reads -> no pad needed)
//   [1024:3104) s_wzk  (32 x 65)
//   [3104:8480) U (5376 floats), phase-unioned:
//     P0/P1: z_m 16x64 at U[0:1024), z_k 32x64 at U[1024:3072)
//     P2/P3: Wedge 64x65 at U[0:4160)
//     P5:    mnm U[0:1024), mnk U[1024:3072), store-scratch U[3072:5376)
//            (4 waves x 576 = 16 rows x 36 stride, 16B-aligned rows)
__global__ __launch_bounds__(256, 3) void gnn_edges(
    const float* __restrict__ z_mk, const float* __restrict__ z_m,
    const float* __restrict__ z_k,  const float* __restrict__ Wedge,
    const float* __restrict__ Wm,   const float* __restrict__ Wk,
    float* __restrict__ out0, float* __restrict__ ws)
{
    __shared__ __align__(16) float s_all[8480];
    float* s_wzm = s_all;          // 1024
    float* s_wzk = s_all + 1024;   // 2080
    float* U     = s_all + 3104;   // 5376

    const int tid  = threadIdx.x;
    const int bid  = blockIdx.x;
    const int b    = bid >> 2;
    const int mq   = bid & 3;      // m-quarter: m = mq*16 .. mq*16+15
    const int lane = tid & 63;
    const int wave = tid >> 6;     // 0..3
    const int low  = lane & 15;
    const int gr   = lane >> 4;
    const int f    = lane;

    // ---- P0: stage z_m quarter (16 rows) + z_k (32 rows) ----
    {
        const float4* src = (const float4*)(z_m + ((size_t)b * Mn + mq * 16) * Fn);
        float4* dst = (float4*)U;
        for (int i = tid; i < 16 * Fn / 4; i += 256) dst[i] = src[i];
        const float4* src2 = (const float4*)(z_k + (size_t)b * Kn * Fn);
        float4* dst2 = (float4*)(U + 1024);
        for (int i = tid; i < Kn * Fn / 4; i += 256) dst2[i] = src2[i];
    }
    __syncthreads();

    // ---- P1: Wz_m (16 rows), Wz_k (32 rows), fp32 ----
    {
        float acc[4] = {0.f, 0.f, 0.f, 0.f};
        for (int c0 = 0; c0 < Fn; c0 += 16) {
            float w[16];
            #pragma unroll
            for (int cc = 0; cc < 16; ++cc) w[cc] = Wm[(c0 + cc) * Fn + f];
            #pragma unroll
            for (int t = 0; t < 4; ++t) {
                const float* zp = U + (wave + 4 * t) * Fn + c0;
                #pragma unroll
                for (int q = 0; q < 4; ++q) {
                    float4 z = *(const float4*)(zp + q * 4);
                    acc[t] += z.x * w[4*q] + z.y * w[4*q+1] + z.z * w[4*q+2] + z.w * w[4*q+3];
                }
            }
        }
        #pragma unroll
        for (int t = 0; t < 4; ++t) s_wzm[(wave + 4 * t) * Fn + f] = acc[t];
    }
    {
        float acc[8] = {0.f};
        for (int c0 = 0; c0 < Fn; c0 += 16) {
            float w[16];
            #pragma unroll
            for (int cc = 0; cc < 16; ++cc) w[cc] = Wk[(c0 + cc) * Fn + f];
            #pragma unroll
            for (int t = 0; t < 8; ++t) {
                const float* zp = U + 1024 + (wave + 4 * t) * Fn + c0;
                #pragma unroll
                for (int q = 0; q < 4; ++q) {
                    float4 z = *(const float4*)(zp + q * 4);
                    acc[t] += z.x * w[4*q] + z.y * w[4*q+1] + z.z * w[4*q+2] + z.w * w[4*q+3];
                }
            }
        }
        #pragma unroll
        for (int t = 0; t < 8; ++t) s_wzk[(wave + 4 * t) * 65 + f] = acc[t];
    }
    __syncthreads();   // z staging dead

    // ---- P2: stage Wedge (padded 65) ----
    for (int i = tid; i < Fn * Fn; i += 256)
        U[(i >> 6) * 65 + (i & 63)] = Wedge[i];
    __syncthreads();

    // ---- P3: B fragments ----
    bf16x8_t Bf[2][4];
    #pragma unroll
    for (int ks = 0; ks < 2; ++ks)
        #pragma unroll
        for (int n = 0; n < 4; ++n)
            #pragma unroll
            for (int i = 0; i < 8; ++i)
                Bf[ks][n][i] = (__bf16)U[(ks * 32 + gr * 8 + i) * 65 + n * 16 + low];
    __syncthreads();   // Wedge dead

    // ---- P4: zero message accumulators ----
    for (int i = tid; i < 3072; i += 256) U[i] = 0.f;
    __syncthreads();

    float* s_mnm = U;                      // 16 x 64
    float* s_mnk = U + 1024;               // 32 x 64
    float* scr   = U + 3072 + wave * 576;  // 16 rows x 36 stride

    // ---- P5: main edge loop ----
    float nk[4][4];
    #pragma unroll
    for (int j = 0; j < 4; ++j)
        #pragma unroll
        for (int n = 0; n < 4; ++n) nk[j][n] = 0.f;

    const int p = wave & 1;                      // == t_local & 1
    const size_t browbase = (size_t)b * ROWS + (size_t)mq * 512;

    for (int it = 0; it < 8; ++it) {
        const int tl = wave + 4 * it;            // 0..31 local tile
        const int m_local = tl >> 1;
        const size_t rowbase = browbase + tl * 16;
        const float* zr = z_mk + (rowbase + low) * 64;

        bf16x8_t A[2];
        #pragma unroll
        for (int ks = 0; ks < 2; ++ks) {
            float4 q0 = *(const float4*)(zr + ks * 32 + gr * 8);
            float4 q1 = *(const float4*)(zr + ks * 32 + gr * 8 + 4);
            A[ks][0] = (__bf16)q0.x; A[ks][1] = (__bf16)q0.y;
            A[ks][2] = (__bf16)q0.z; A[ks][3] = (__bf16)q0.w;
            A[ks][4] = (__bf16)q1.x; A[ks][5] = (__bf16)q1.y;
            A[ks][6] = (__bf16)q1.z; A[ks][7] = (__bf16)q1.w;
        }

        f32x4_t acc[4];
        #pragma unroll
        for (int n = 0; n < 4; ++n) acc[n] = (f32x4_t){0.f, 0.f, 0.f, 0.f};
        #pragma unroll
        for (int ks = 0; ks < 2; ++ks)
            #pragma unroll
            for (int n = 0; n < 4; ++n)
                acc[n] = __builtin_amdgcn_mfma_f32_16x16x32_bf16(A[ks], Bf[ks][n], acc[n], 0, 0, 0);

        // epilogue: msgs + LDS transpose -> 128B-aligned full-line stores
        #pragma unroll
        for (int h = 0; h < 2; ++h) {
            #pragma unroll
            for (int nn = 0; nn < 2; ++nn) {
                const int n  = h * 2 + nn;
                const int fc = n * 16 + low;
                const float wmv = s_wzm[m_local * Fn + fc];
                float snm = 0.f;
                #pragma unroll
                for (int j = 0; j < 4; ++j) {
                    const int kk = p * 16 + gr * 4 + j;
                    float e = acc[n][j] + wmv + s_wzk[kk * 65 + fc];
                    e = e > 0.f ? e : 0.01f * e;
                    scr[(gr * 4 + j) * 36 + nn * 16 + low] = e;
                    nk[j][n] += e;
                    snm += e;
                }
                snm += __shfl_xor(snm, 16);
                snm += __shfl_xor(snm, 32);
                if (gr == 0) atomicAdd(&s_mnm[m_local * Fn + fc], snm);
            }
            __builtin_amdgcn_wave_barrier();
            #pragma unroll
            for (int q = 0; q < 2; ++q) {
                float4 v = *(const float4*)(scr + (q * 8 + (lane >> 3)) * 36 + (lane & 7) * 4);
                *(float4*)(out0 + (rowbase + q * 8 + (lane >> 3)) * 64 + h * 32 + (lane & 7) * 4) = v;
            }
            __builtin_amdgcn_wave_barrier();
        }
    }

    // flush per-lane msg_nk partials into LDS
    #pragma unroll
    for (int j = 0; j < 4; ++j)
        #pragma unroll
        for (int n = 0; n < 4; ++n)
            atomicAdd(&s_mnk[(p * 16 + gr * 4 + j) * Fn + n * 16 + low], nk[j][n]);
    __syncthreads();

    // ---- P6: messages to workspace ----
    {
        float* dm = ws + (size_t)b * (Mn * Fn) + mq * 16 * Fn;       // complete rows
        for (int i = tid; i < 1024; i += 256) dm[i] = s_mnm[i];
        float* dk = ws + (size_t)BS * Mn * Fn + ((size_t)mq * BS + b) * (Kn * Fn); // partial
        for (int i = tid; i < 2048; i += 256) dk[i] = s_mnk[i];
    }
}

// ---------------- Kernel B: node updates -----------------
// grid 512 (one block per batch), 256 threads (4 waves).
__global__ __launch_bounds__(256, 2) void gnn_nodes(
    const float* __restrict__ z_m, const float* __restrict__ z_k,
    const float* __restrict__ Wself_m, const float* __restrict__ Wself_k,
    const float* __restrict__ Wneigh_m, const float* __restrict__ Wneigh_k,
    const float* __restrict__ ws,
    float* __restrict__ out1, float* __restrict__ out2)
{
    __shared__ __align__(16) float s[12288]; // zm 4096 | zk 2048 | mnm 4096 | mnk 2048
    float* s_zm  = s;
    float* s_zk  = s + 4096;
    float* s_mnm = s + 6144;
    float* s_mnk = s + 10240;

    const int tid  = threadIdx.x;
    const int b    = blockIdx.x;
    const int lane = tid & 63;
    const int wave = tid >> 6;
    const int f    = lane;
    const int rg   = wave;

    {
        const float4* src = (const float4*)(z_m + (size_t)b * Mn * Fn);
        for (int i = tid; i < Mn * Fn / 4; i += 256) ((float4*)s_zm)[i] = src[i];
        const float4* src2 = (const float4*)(z_k + (size_t)b * Kn * Fn);
        for (int i = tid; i < Kn * Fn / 4; i += 256) ((float4*)s_zk)[i] = src2[i];
        const float4* srcm = (const float4*)(ws + (size_t)b * Mn * Fn);
        for (int i = tid; i < Mn * Fn / 4; i += 256) ((float4*)s_mnm)[i] = srcm[i];
        const float* base = ws + (size_t)BS * Mn * Fn;
        const float* p0 = base + ((size_t)0 * BS + b) * (Kn * Fn);
        const float* p1 = base + ((size_t)1 * BS + b) * (Kn * Fn);
        const float* p2 = base + ((size_t)2 * BS + b) * (Kn * Fn);
        const float* p3 = base + ((size_t)3 * BS + b) * (Kn * Fn);
        for (int i = tid; i < Kn * Fn; i += 256) s_mnk[i] = p0[i] + p1[i] + p2[i] + p3[i];
    }
    __syncthreads();

    // out1: rows rg + 4t, t=0..15
    {
        float d[16], e[16];
        #pragma unroll
        for (int t = 0; t < 16; ++t) { d[t] = 0.f; e[t] = 0.f; }
        for (int c0 = 0; c0 < Fn; c0 += 16) {
            float wA[16], wB[16];
            #pragma unroll
            for (int cc = 0; cc < 16; ++cc) {
                wA[cc] = Wself_m[(c0 + cc) * Fn + f];
                wB[cc] = Wneigh_m[(c0 + cc) * Fn + f];
            }
            #pragma unroll
            for (int t = 0; t < 16; ++t) {
                const float* zp = s_zm + (rg + 4 * t) * Fn + c0;
                const float* mp = s_mnm + (rg + 4 * t) * Fn + c0;
                #pragma unroll
                for (int q = 0; q < 4; ++q) {
                    float4 z = *(const float4*)(zp + q * 4);
                    float4 m = *(const float4*)(mp + q * 4);
                    d[t] += z.x * wA[4*q] + z.y * wA[4*q+1] + z.z * wA[4*q+2] + z.w * wA[4*q+3];
                    e[t] += m.x * wB[4*q] + m.y * wB[4*q+1] + m.z * wB[4*q+2] + m.w * wB[4*q+3];
                }
            }
        }
        #pragma unroll
        for (int t = 0; t < 16; ++t) {
            float v = d[t] + e[t] * (1.f / 32.f);
            v = v > 0.f ? v : 0.01f * v;
            out1[(size_t)b * Mn * Fn + (rg + 4 * t) * Fn + f] = v;
        }
    }
    // out2: rows rg + 4t, t=0..7
    {
        float d[8], e[8];
        #pragma unroll
        for (int t = 0; t < 8; ++t) { d[t] = 0.f; e[t] = 0.f; }
        for (int c0 = 0; c0 < Fn; c0 += 16) {
            float wA[16], wB[16];
            #pragma unroll
            for (int cc = 0; cc < 16; ++cc) {
                wA[cc] = Wself_k[(c0 + cc) * Fn + f];
                wB[cc] = Wneigh_k[(c0 + cc) * Fn + f];
            }
            #pragma unroll
            for (int t = 0; t < 8; ++t) {
                const float* zp = s_zk + (rg + 4 * t) * Fn + c0;
                const float* mp = s_mnk + (rg + 4 * t) * Fn + c0;
                #pragma unroll
                for (int q = 0; q < 4; ++q) {
                    float4 z = *(const float4*)(zp + q * 4);
                    float4 m = *(const float4*)(mp + q * 4);
                    d[t] += z.x * wA[4*q] + z.y * wA[4*q+1] + z.z * wA[4*q+2] + z.w * wA[4*q+3];
                    e[t] += m.x * wB[4*q] + m.y * wB[4*q+1] + m.z * wB[4*q+2] + m.w * wB[4*q+3];
                }
            }
        }
        #pragma unroll
        for (int t = 0; t < 8; ++t) {
            float v = d[t] + e[t] * (1.f / 64.f);
            v = v > 0.f ? v : 0.01f * v;
            out2[(size_t)b * Kn * Fn + (rg + 4 * t) * Fn + f] = v;
        }
    }
}

extern "C" void kernel_launch(void* const* d_in, const int* in_sizes, int n_in,
                              void* d_out, int out_size, void* d_ws, size_t ws_size,
                              hipStream_t stream) {
    const float* z_mk     = (const float*)d_in[0];
    const float* z_m      = (const float*)d_in[1];
    const float* z_k      = (const float*)d_in[2];
    const float* Wedge    = (const float*)d_in[3];
    const float* Wm       = (const float*)d_in[4];
    const float* Wk       = (const float*)d_in[5];
    const float* Wself_m  = (const float*)d_in[6];
    const float* Wself_k  = (const float*)d_in[7];
    const float* Wneigh_m = (const float*)d_in[8];
    const float* Wneigh_k = (const float*)d_in[9];

    float* out0 = (float*)d_out;                       // (512, 2048, 64)
    float* out1 = out0 + (size_t)BS * ROWS * Fn;       // (512, 64, 64)
    float* out2 = out1 + (size_t)BS * Mn * Fn;         // (512, 32, 64)
    float* ws   = (float*)d_ws;                        // 25.2 MB used

    gnn_edges<<<BS * 4, 256, 0, stream>>>(z_mk, z_m, z_k, Wedge, Wm, Wk, out0, ws);
    gnn_nodes<<<BS, 256, 0, stream>>>(z_m, z_k, Wself_m, Wself_k,
                                      Wneigh_m, Wneigh_k, ws, out1, out2);
}

// Round 5
// 185.733 us; speedup vs baseline: 4.7244x; 1.1026x over previous
//
#include <hip/hip_runtime.h>

typedef float  f32x4_t  __attribute__((ext_vector_type(4)));
typedef __bf16 bf16x8_t __attribute__((ext_vector_type(8)));

#define BS   512
#define Mn   64
#define Kn   32
#define Fn   64
#define ROWS 2048   // Mn*Kn

// ---------------- Kernel A: edges + messages -----------------
// grid 2048 = 512 batches x 4 m-quarters; 256 threads (4 waves).
// Per iteration each wave processes a PAIR of 16-row tiles (t, t+4) with both
// A-tile loads issued up front: tile-1's HBM latency hides under tile-0's
// MFMA + epilogue. s_wzk reads hoisted to registers (loop-invariant).
// out0 stores are nontemporal (streamed, never re-read) to keep z_mk in L3.
__global__ __launch_bounds__(256, 3) void gnn_edges(
    const float* __restrict__ z_mk, const float* __restrict__ z_m,
    const float* __restrict__ z_k,  const float* __restrict__ Wedge,
    const float* __restrict__ Wm,   const float* __restrict__ Wk,
    float* __restrict__ out0, float* __restrict__ ws)
{
    __shared__ __align__(16) float s_all[8480];
    float* s_wzm = s_all;          // 1024 (16 x 64)
    float* s_wzk = s_all + 1024;   // 2080 (32 x 65)
    float* U     = s_all + 3104;   // 5376 phase-unioned

    const int tid  = threadIdx.x;
    const int bid  = blockIdx.x;
    const int b    = bid >> 2;
    const int mq   = bid & 3;      // m-quarter
    const int lane = tid & 63;
    const int wave = tid >> 6;     // 0..3
    const int low  = lane & 15;
    const int gr   = lane >> 4;
    const int f    = lane;

    // ---- P0: stage z_m quarter (16 rows) + z_k (32 rows) ----
    {
        const float4* src = (const float4*)(z_m + ((size_t)b * Mn + mq * 16) * Fn);
        float4* dst = (float4*)U;
        for (int i = tid; i < 16 * Fn / 4; i += 256) dst[i] = src[i];
        const float4* src2 = (const float4*)(z_k + (size_t)b * Kn * Fn);
        float4* dst2 = (float4*)(U + 1024);
        for (int i = tid; i < Kn * Fn / 4; i += 256) dst2[i] = src2[i];
    }
    __syncthreads();

    // ---- P1: Wz_m (16 rows), Wz_k (32 rows), fp32 ----
    {
        float acc[4] = {0.f, 0.f, 0.f, 0.f};
        for (int c0 = 0; c0 < Fn; c0 += 16) {
            float w[16];
            #pragma unroll
            for (int cc = 0; cc < 16; ++cc) w[cc] = Wm[(c0 + cc) * Fn + f];
            #pragma unroll
            for (int t = 0; t < 4; ++t) {
                const float* zp = U + (wave + 4 * t) * Fn + c0;
                #pragma unroll
                for (int q = 0; q < 4; ++q) {
                    float4 z = *(const float4*)(zp + q * 4);
                    acc[t] += z.x * w[4*q] + z.y * w[4*q+1] + z.z * w[4*q+2] + z.w * w[4*q+3];
                }
            }
        }
        #pragma unroll
        for (int t = 0; t < 4; ++t) s_wzm[(wave + 4 * t) * Fn + f] = acc[t];
    }
    {
        float acc[8] = {0.f};
        for (int c0 = 0; c0 < Fn; c0 += 16) {
            float w[16];
            #pragma unroll
            for (int cc = 0; cc < 16; ++cc) w[cc] = Wk[(c0 + cc) * Fn + f];
            #pragma unroll
            for (int t = 0; t < 8; ++t) {
                const float* zp = U + 1024 + (wave + 4 * t) * Fn + c0;
                #pragma unroll
                for (int q = 0; q < 4; ++q) {
                    float4 z = *(const float4*)(zp + q * 4);
                    acc[t] += z.x * w[4*q] + z.y * w[4*q+1] + z.z * w[4*q+2] + z.w * w[4*q+3];
                }
            }
        }
        #pragma unroll
        for (int t = 0; t < 8; ++t) s_wzk[(wave + 4 * t) * 65 + f] = acc[t];
    }
    __syncthreads();   // z staging dead

    // ---- P2: stage Wedge (padded 65) ----
    for (int i = tid; i < Fn * Fn; i += 256)
        U[(i >> 6) * 65 + (i & 63)] = Wedge[i];
    __syncthreads();

    // ---- P3: B fragments ----
    bf16x8_t Bf[2][4];
    #pragma unroll
    for (int ks = 0; ks < 2; ++ks)
        #pragma unroll
        for (int n = 0; n < 4; ++n)
            #pragma unroll
            for (int i = 0; i < 8; ++i)
                Bf[ks][n][i] = (__bf16)U[(ks * 32 + gr * 8 + i) * 65 + n * 16 + low];
    __syncthreads();   // Wedge dead

    // ---- P4: zero message accumulators ----
    for (int i = tid; i < 3072; i += 256) U[i] = 0.f;

    // hoist loop-invariant Wz_k values: kk = p*16 + gr*4 + j, fc = n*16 + low
    const int p = wave & 1;
    float wzk_r[4][4];
    #pragma unroll
    for (int j = 0; j < 4; ++j)
        #pragma unroll
        for (int n = 0; n < 4; ++n)
            wzk_r[j][n] = s_wzk[(p * 16 + gr * 4 + j) * 65 + n * 16 + low];
    __syncthreads();

    float* s_mnm = U;                      // 16 x 64
    float* s_mnk = U + 1024;               // 32 x 64
    float* scr   = U + 3072 + wave * 576;  // 16 rows x 36 stride

    // ---- P5: main edge loop, tile pairs ----
    float nk[4][4];
    #pragma unroll
    for (int j = 0; j < 4; ++j)
        #pragma unroll
        for (int n = 0; n < 4; ++n) nk[j][n] = 0.f;

    const size_t browbase = (size_t)b * ROWS + (size_t)mq * 512;

    for (int it = 0; it < 4; ++it) {
        const int t0 = wave + 8 * it;        // tiles: wave parity preserved
        const int t1 = t0 + 4;
        const int m0 = t0 >> 1;
        const int m1 = t1 >> 1;
        const size_t rb0 = browbase + t0 * 16;
        const size_t rb1 = browbase + t1 * 16;

        // issue ALL 8 loads for the pair up front (MLP)
        const float* zr0 = z_mk + (rb0 + low) * 64;
        const float* zr1 = z_mk + (rb1 + low) * 64;
        float4 r0[4], r1[4];
        #pragma unroll
        for (int ks = 0; ks < 2; ++ks) {
            r0[2*ks]   = *(const float4*)(zr0 + ks * 32 + gr * 8);
            r0[2*ks+1] = *(const float4*)(zr0 + ks * 32 + gr * 8 + 4);
            r1[2*ks]   = *(const float4*)(zr1 + ks * 32 + gr * 8);
            r1[2*ks+1] = *(const float4*)(zr1 + ks * 32 + gr * 8 + 4);
        }

        #pragma unroll
        for (int half = 0; half < 2; ++half) {
            const float4* rr = half ? r1 : r0;
            const int     ml = half ? m1 : m0;
            const size_t  rb = half ? rb1 : rb0;

            bf16x8_t A[2];
            #pragma unroll
            for (int ks = 0; ks < 2; ++ks) {
                float4 qa = rr[2*ks], qb = rr[2*ks+1];
                A[ks][0] = (__bf16)qa.x; A[ks][1] = (__bf16)qa.y;
                A[ks][2] = (__bf16)qa.z; A[ks][3] = (__bf16)qa.w;
                A[ks][4] = (__bf16)qb.x; A[ks][5] = (__bf16)qb.y;
                A[ks][6] = (__bf16)qb.z; A[ks][7] = (__bf16)qb.w;
            }

            f32x4_t acc[4];
            #pragma unroll
            for (int n = 0; n < 4; ++n) acc[n] = (f32x4_t){0.f, 0.f, 0.f, 0.f};
            #pragma unroll
            for (int ks = 0; ks < 2; ++ks)
                #pragma unroll
                for (int n = 0; n < 4; ++n)
                    acc[n] = __builtin_amdgcn_mfma_f32_16x16x32_bf16(A[ks], Bf[ks][n], acc[n], 0, 0, 0);

            // epilogue: msgs + LDS transpose -> nontemporal full-line stores
            #pragma unroll
            for (int h = 0; h < 2; ++h) {
                #pragma unroll
                for (int nn = 0; nn < 2; ++nn) {
                    const int n  = h * 2 + nn;
                    const int fc = n * 16 + low;
                    const float wmv = s_wzm[ml * Fn + fc];
                    float snm = 0.f;
                    #pragma unroll
                    for (int j = 0; j < 4; ++j) {
                        float e = acc[n][j] + wmv + wzk_r[j][n];
                        e = e > 0.f ? e : 0.01f * e;
                        scr[(gr * 4 + j) * 36 + nn * 16 + low] = e;
                        nk[j][n] += e;
                        snm += e;
                    }
                    snm += __shfl_xor(snm, 16);
                    snm += __shfl_xor(snm, 32);
                    if (gr == 0) atomicAdd(&s_mnm[ml * Fn + fc], snm);
                }
                __builtin_amdgcn_wave_barrier();
                #pragma unroll
                for (int q = 0; q < 2; ++q) {
                    f32x4_t v = *(const f32x4_t*)(scr + (q * 8 + (lane >> 3)) * 36 + (lane & 7) * 4);
                    __builtin_nontemporal_store(v,
                        (f32x4_t*)(out0 + (rb + q * 8 + (lane >> 3)) * 64 + h * 32 + (lane & 7) * 4));
                }
                __builtin_amdgcn_wave_barrier();
            }
        }
    }

    // flush per-lane msg_nk partials into LDS
    #pragma unroll
    for (int j = 0; j < 4; ++j)
        #pragma unroll
        for (int n = 0; n < 4; ++n)
            atomicAdd(&s_mnk[(p * 16 + gr * 4 + j) * Fn + n * 16 + low], nk[j][n]);
    __syncthreads();

    // ---- P6: messages to workspace ----
    {
        float* dm = ws + (size_t)b * (Mn * Fn) + mq * 16 * Fn;       // complete rows
        for (int i = tid; i < 1024; i += 256) dm[i] = s_mnm[i];
        float* dk = ws + (size_t)BS * Mn * Fn + ((size_t)mq * BS + b) * (Kn * Fn); // partial
        for (int i = tid; i < 2048; i += 256) dk[i] = s_mnk[i];
    }
}

// ---------------- Kernel B: node updates -----------------
__global__ __launch_bounds__(256, 2) void gnn_nodes(
    const float* __restrict__ z_m, const float* __restrict__ z_k,
    const float* __restrict__ Wself_m, const float* __restrict__ Wself_k,
    const float* __restrict__ Wneigh_m, const float* __restrict__ Wneigh_k,
    const float* __restrict__ ws,
    float* __restrict__ out1, float* __restrict__ out2)
{
    __shared__ __align__(16) float s[12288]; // zm 4096 | zk 2048 | mnm 4096 | mnk 2048
    float* s_zm  = s;
    float* s_zk  = s + 4096;
    float* s_mnm = s + 6144;
    float* s_mnk = s + 10240;

    const int tid  = threadIdx.x;
    const int b    = blockIdx.x;
    const int lane = tid & 63;
    const int wave = tid >> 6;
    const int f    = lane;
    const int rg   = wave;

    {
        const float4* src = (const float4*)(z_m + (size_t)b * Mn * Fn);
        for (int i = tid; i < Mn * Fn / 4; i += 256) ((float4*)s_zm)[i] = src[i];
        const float4* src2 = (const float4*)(z_k + (size_t)b * Kn * Fn);
        for (int i = tid; i < Kn * Fn / 4; i += 256) ((float4*)s_zk)[i] = src2[i];
        const float4* srcm = (const float4*)(ws + (size_t)b * Mn * Fn);
        for (int i = tid; i < Mn * Fn / 4; i += 256) ((float4*)s_mnm)[i] = srcm[i];
        const float* base = ws + (size_t)BS * Mn * Fn;
        const float* p0 = base + ((size_t)0 * BS + b) * (Kn * Fn);
        const float* p1 = base + ((size_t)1 * BS + b) * (Kn * Fn);
        const float* p2 = base + ((size_t)2 * BS + b) * (Kn * Fn);
        const float* p3 = base + ((size_t)3 * BS + b) * (Kn * Fn);
        for (int i = tid; i < Kn * Fn; i += 256) s_mnk[i] = p0[i] + p1[i] + p2[i] + p3[i];
    }
    __syncthreads();

    // out1: rows rg + 4t, t=0..15
    {
        float d[16], e[16];
        #pragma unroll
        for (int t = 0; t < 16; ++t) { d[t] = 0.f; e[t] = 0.f; }
        for (int c0 = 0; c0 < Fn; c0 += 16) {
            float wA[16], wB[16];
            #pragma unroll
            for (int cc = 0; cc < 16; ++cc) {
                wA[cc] = Wself_m[(c0 + cc) * Fn + f];
                wB[cc] = Wneigh_m[(c0 + cc) * Fn + f];
            }
            #pragma unroll
            for (int t = 0; t < 16; ++t) {
                const float* zp = s_zm + (rg + 4 * t) * Fn + c0;
                const float* mp = s_mnm + (rg + 4 * t) * Fn + c0;
                #pragma unroll
                for (int q = 0; q < 4; ++q) {
                    float4 z = *(const float4*)(zp + q * 4);
                    float4 m = *(const float4*)(mp + q * 4);
                    d[t] += z.x * wA[4*q] + z.y * wA[4*q+1] + z.z * wA[4*q+2] + z.w * wA[4*q+3];
                    e[t] += m.x * wB[4*q] + m.y * wB[4*q+1] + m.z * wB[4*q+2] + m.w * wB[4*q+3];
                }
            }
        }
        #pragma unroll
        for (int t = 0; t < 16; ++t) {
            float v = d[t] + e[t] * (1.f / 32.f);
            v = v > 0.f ? v : 0.01f * v;
            out1[(size_t)b * Mn * Fn + (rg + 4 * t) * Fn + f] = v;
        }
    }
    // out2: rows rg + 4t, t=0..7
    {
        float d[8], e[8];
        #pragma unroll
        for (int t = 0; t < 8; ++t) { d[t] = 0.f; e[t] = 0.f; }
        for (int c0 = 0; c0 < Fn; c0 += 16) {
            float wA[16], wB[16];
            #pragma unroll
            for (int cc = 0; cc < 16; ++cc) {
                wA[cc] = Wself_k[(c0 + cc) * Fn + f];
                wB[cc] = Wneigh_k[(c0 + cc) * Fn + f];
            }
            #pragma unroll
            for (int t = 0; t < 8; ++t) {
                const float* zp = s_zk + (rg + 4 * t) * Fn + c0;
                const float* mp = s_mnk + (rg + 4 * t) * Fn + c0;
                #pragma unroll
                for (int q = 0; q < 4; ++q) {
                    float4 z = *(const float4*)(zp + q * 4);
                    float4 m = *(const float4*)(mp + q * 4);
                    d[t] += z.x * wA[4*q] + z.y * wA[4*q+1] + z.z * wA[4*q+2] + z.w * wA[4*q+3];
                    e[t] += m.x * wB[4*q] + m.y * wB[4*q+1] + m.z * wB[4*q+2] + m.w * wB[4*q+3];
                }
            }
        }
        #pragma unroll
        for (int t = 0; t < 8; ++t) {
            float v = d[t] + e[t] * (1.f / 64.f);
            v = v > 0.f ? v : 0.01f * v;
            out2[(size_t)b * Kn * Fn + (rg + 4 * t) * Fn + f] = v;
        }
    }
}

extern "C" void kernel_launch(void* const* d_in, const int* in_sizes, int n_in,
                              void* d_out, int out_size, void* d_ws, size_t ws_size,
                              hipStream_t stream) {
    const float* z_mk     = (const float*)d_in[0];
    const float* z_m      = (const float*)d_in[1];
    const float* z_k      = (const float*)d_in[2];
    const float* Wedge    = (const float*)d_in[3];
    const float* Wm       = (const float*)d_in[4];
    const float* Wk       = (const float*)d_in[5];
    const float* Wself_m  = (const float*)d_in[6];
    const float* Wself_k  = (const float*)d_in[7];
    const float* Wneigh_m = (const float*)d_in[8];
    const float* Wneigh_k = (const float*)d_in[9];

    float* out0 = (float*)d_out;                       // (512, 2048, 64)
    float* out1 = out0 + (size_t)BS * ROWS * Fn;       // (512, 64, 64)
    float* out2 = out1 + (size_t)BS * Mn * Fn;         // (512, 32, 64)
    float* ws   = (float*)d_ws;                        // 25.2 MB used

    gnn_edges<<<BS * 4, 256, 0, stream>>>(z_mk, z_m, z_k, Wedge, Wm, Wk, out0, ws);
    gnn_nodes<<<BS, 256, 0, stream>>>(z_m, z_k, Wself_m, Wself_k,
                                      Wneigh_m, Wneigh_k, ws, out1, out2);
}